// Round 15
// baseline (147.972 us; speedup 1.0000x reference)
//
#include <hip/hip_runtime.h>

#define B_  16
#define L_  1024
#define E_  256
#define H_  8
#define DH_ 32
#define M_  (B_ * L_)                 // 16384 rows
#define SCALE_L2E 0.25501817656f      // (1/sqrt(32)) * log2(e)

typedef unsigned short u16;
typedef unsigned int   u32;
typedef short bf8_t __attribute__((ext_vector_type(8)));   // 8 bf16 (4 VGPRs)
typedef float f4_t  __attribute__((ext_vector_type(4)));   // MFMA acc 16x16
typedef float f16f  __attribute__((ext_vector_type(16)));  // MFMA acc 32x32
union F4U { uint4 u; bf8_t s; };

static __device__ __forceinline__ float bf2f(u16 u) {
    return __uint_as_float(((u32)u) << 16);
}
static __device__ __forceinline__ u16 f2bf(float f) {
    u32 u = __float_as_uint(f);
    u32 r = 0x7FFFu + ((u >> 16) & 1u);   // RNE
    return (u16)((u + r) >> 16);
}
// hardware packed f32->bf16x2 convert (RNE), 1 VALU op
static __device__ __forceinline__ u32 cvt_pk_bf16(float a, float b) {
    u32 r;
    asm("v_cvt_pk_bf16_f32 %0, %1, %2" : "=v"(r) : "v"(a), "v"(b));
    return r;
}

// ---- kernel 1: LN'd embedding TABLE (l x class, 4096 rows) + W->bf16 convert.
// weights stored in MFMA-FRAGMENT order w_f[n>>4][k>>5][n&15][k&31] (R13).
__global__ __launch_bounds__(256) void table_conv_k(
    const float* __restrict__ emb_w,      // [L,E,4] fp32
    const float* __restrict__ emb_b,      // [L,E]
    const float* __restrict__ in_proj_w,  // [768,256] fp32
    const float* __restrict__ out_w,      // [256,256] fp32
    u16* __restrict__ tbl,                // [L,4,E] bf16 (LN'd)
    u16* __restrict__ wcvt)               // [768*256 + 256*256] bf16 fragment-order
{
    __shared__ float sm[256][5];          // [element e][class c], pad 5
    int blk = blockIdx.x, tid = threadIdx.x;
    {   // weight conversion -> fragment order: 1024 blocks x 256 threads
        int idx = blk * 256 + tid;
        float v = (idx < 196608) ? in_proj_w[idx] : out_w[idx - 196608];
        int base = (idx < 196608) ? 0 : 196608;
        int rel = idx - base;
        int n = rel >> 8, k = rel & 255;
        wcvt[base + ((n >> 4) * 4096 + (k >> 5) * 512 + (n & 15) * 32 + (k & 31))] = f2bf(v);
    }
    int w = tid >> 6, lane = tid & 63;
    int l = blk;
    {   // coalesced: thread tid loads all 4 classes of element e=tid
        float4 v = *(const float4*)(emb_w + (size_t)l * 1024 + tid * 4);
        sm[tid][0] = v.x; sm[tid][1] = v.y; sm[tid][2] = v.z; sm[tid][3] = v.w;
    }
    __syncthreads();
    float4 bb = *(const float4*)(emb_b + (size_t)l * 256 + lane * 4);
    float bv[4] = {bb.x, bb.y, bb.z, bb.w};
    float x[4], s = 0.f, q = 0.f;
    #pragma unroll
    for (int j = 0; j < 4; ++j) {
        float t = sm[lane * 4 + j][w] + bv[j];   // class w of element lane*4+j
        x[j] = t; s += t; q += t * t;
    }
    #pragma unroll
    for (int off = 1; off < 64; off <<= 1) {
        s += __shfl_xor(s, off);
        q += __shfl_xor(q, off);
    }
    float mean = s * (1.0f / 256.0f);
    float var  = q * (1.0f / 256.0f) - mean * mean;
    float rstd = rsqrtf(var + 1e-5f);
    ushort4 o = { f2bf((x[0] - mean) * rstd), f2bf((x[1] - mean) * rstd),
                  f2bf((x[2] - mean) * rstd), f2bf((x[3] - mean) * rstd) };
    *(ushort4*)(tbl + ((size_t)l * 4 + w) * 256 + lane * 4) = o;
}

// ---- kernel 1b: resolve seq ONCE -> pre-gathered A in fragment order.
// af[(m>>4)*8 + (k>>5)][(m&15)*32 + (k&31)] = LN'd emb(m, k).
// af ALIASES the ctx region (liveness disjoint: af dies after gemm; ctx is
// fully overwritten by attn before proj reads it) -> ws footprint = R13's.
__global__ __launch_bounds__(256) void gather_a_k(
    const int* __restrict__ seq,      // [M]
    const u16* __restrict__ tbl,      // [L,4,256] bf16
    u16* __restrict__ af)             // [M/16][8][16][32] bf16 fragment-order
{
    int i = blockIdx.x * 256 + threadIdx.x;     // 524288 threads, 8 els each
    int m = i >> 5, c = i & 31;
    int cls = seq[m];
    uint4 v = *(const uint4*)(tbl + ((size_t)((m & 1023) * 4 + cls)) * 256 + c * 8);
    *(uint4*)(af + ((size_t)((m >> 4) * 8 + (c >> 2))) * 512 + (m & 15) * 32 + (c & 3) * 8) = v;
}

// ---- kernel 2: QKV = emb @ Wqkv^T + b (MFMA, LDS-free), 4 m-tiles per wave.
// v7: ALL loads dense 1 KB wave-loads (fragment-order A from gather_a_k,
// fragment-order B from table_conv). No seq indirection in the hot loop.
// V stored in fragment order vt[bh][g][lane][8] with bit-2/3 key swap (R12).
__global__ __launch_bounds__(256, 2) void gemm_qkv_mfma_k(
    const u16* __restrict__ af,       // [M/16][8][16][32] bf16 fragment-order
    const u16* __restrict__ wqkv,     // [48][8][16][32] bf16 fragment-order
    const float* __restrict__ bias,   // [768] fp32
    u16* __restrict__ q_s, u16* __restrict__ k_s, u16* __restrict__ vt)
{
    int tid = threadIdx.x;
    int w = tid >> 6, lane = tid & 63, l15 = lane & 15, quad = lane >> 4;
    int n0 = blockIdx.x * 64, m0 = blockIdx.y * 256;
    int b = m0 >> 10;

    const u16* Apt[4];
    #pragma unroll
    for (int t = 0; t < 4; ++t)
        Apt[t] = af + ((size_t)((m0 >> 4) + w * 4 + t) * 8) * 512 + l15 * 32 + quad * 8;
    // fragment-order B: dense 1 KB per (nb, ks) wave-load
    const u16* Bp = wqkv + (size_t)(n0 >> 4) * 4096 + l15 * 32 + quad * 8;

    f4_t acc[4][4] = {{{0,0,0,0},{0,0,0,0},{0,0,0,0},{0,0,0,0}},
                      {{0,0,0,0},{0,0,0,0},{0,0,0,0},{0,0,0,0}},
                      {{0,0,0,0},{0,0,0,0},{0,0,0,0},{0,0,0,0}},
                      {{0,0,0,0},{0,0,0,0},{0,0,0,0},{0,0,0,0}}};

    if (n0 < 512) {                        // ---- Q or K: transposed C ----
        #pragma unroll
        for (int ks = 0; ks < 8; ++ks) {
            F4U bfr[4];
            #pragma unroll
            for (int nc = 0; nc < 4; ++nc)
                bfr[nc].u = *(const uint4*)(Bp + nc * 4096 + ks * 512);
            #pragma unroll
            for (int t = 0; t < 4; ++t) {
                F4U a; a.u = *(const uint4*)(Apt[t] + ks * 512);
                #pragma unroll
                for (int nc = 0; nc < 4; ++nc)
                    acc[t][nc] = __builtin_amdgcn_mfma_f32_16x16x32_bf16(bfr[nc].s, a.s, acc[t][nc], 0, 0, 0);
            }
        }
        float sc = (n0 < 256) ? SCALE_L2E : 1.0f;
        u16* dst = (n0 < 256) ? q_s : k_s;
        #pragma unroll
        for (int t = 0; t < 4; ++t) {
            int l = (m0 & 1023) + w * 64 + t * 16 + l15;
            #pragma unroll
            for (int nc = 0; nc < 4; ++nc) {
                int nb = n0 + nc * 16 + quad * 4;  // 4 consecutive n = same head
                float4 b4 = *(const float4*)(bias + nb);
                int nl = nb & 255, h = nl >> 5, d0 = nl & 31;
                ushort4 o = { f2bf((acc[t][nc][0] + b4.x) * sc), f2bf((acc[t][nc][1] + b4.y) * sc),
                              f2bf((acc[t][nc][2] + b4.z) * sc), f2bf((acc[t][nc][3] + b4.w) * sc) };
                *(ushort4*)(dst + ((size_t)(b * 8 + h) * 1024 + l) * 32 + d0) = o;
            }
        }
    } else {                               // ---- V: normal C, store fragment-order ----
        #pragma unroll
        for (int ks = 0; ks < 8; ++ks) {
            F4U bfr[4];
            #pragma unroll
            for (int nc = 0; nc < 4; ++nc)
                bfr[nc].u = *(const uint4*)(Bp + nc * 4096 + ks * 512);
            #pragma unroll
            for (int t = 0; t < 4; ++t) {
                F4U a; a.u = *(const uint4*)(Apt[t] + ks * 512);
                #pragma unroll
                for (int nc = 0; nc < 4; ++nc)
                    acc[t][nc] = __builtin_amdgcn_mfma_f32_16x16x32_bf16(a.s, bfr[nc].s, acc[t][nc], 0, 0, 0);
            }
        }
        #pragma unroll
        for (int t = 0; t < 4; ++t) {
            int lq = (m0 & 1023) + w * 64 + t * 16 + quad * 4;  // 4-aligned key base
            // stored position: bit-2/3 swap of within-group key index
            int lqp = (lq & ~12) | ((lq & 4) << 1) | ((lq & 8) >> 1);
            int g  = lq >> 4;          // 16-key group (0..63)
            int q0 = lqp & 15;         // in {0,4,8,12}
            #pragma unroll
            for (int nc = 0; nc < 4; ++nc) {
                int n = n0 + nc * 16 + l15;
                float bv = bias[n];
                int nl = n & 255, h = nl >> 5, d = nl & 31;
                ushort4 o = { f2bf(acc[t][nc][0] + bv), f2bf(acc[t][nc][1] + bv),
                              f2bf(acc[t][nc][2] + bv), f2bf(acc[t][nc][3] + bv) };
                // vt2[bh][g][lane = d + 32*(q0>>3)][8] ; 4 u16 at +(q0&7)
                *(ushort4*)(vt + (((size_t)(b * 8 + h) * 64 + g) * 64 + d + ((q0 >> 3) << 5)) * 8 + (q0 & 7)) = o;
            }
        }
    }
}

// ---- kernel 3: MFMA flash attention (R12 — proven best, fragment-order V).
// 512 blocks, 4 waves, 64 q-rows/wave, 64-key units, no LDS, K/V ping-pong.
// V loads 1 KB fully-coalesced; K loads dense. EXPPACK straight-line.
// NOTE: fully overwrites ctx (every [bh][l][0..31] element) -- required,
// since ctx's region doubles as the af staging buffer earlier in the call.
__global__ __launch_bounds__(256, 2) void attn32_k(
    const u16* __restrict__ q_s,   // [bh][l][32] (pre-scaled by SCALE*log2e)
    const u16* __restrict__ k_s,   // [bh][l][32]
    const u16* __restrict__ vt,    // [bh][64][64][8] fragment-order
    u16* __restrict__ ctx)         // [bh][l][32]
{
    int tid = threadIdx.x;
    int w = tid >> 6, lane = tid & 63, col = lane & 31, hi = lane >> 5;
    int g = blockIdx.x;                      // 512 blocks = 4 qt x 128 bh
    int bh = (g & 7) | ((g >> 5) << 3);      // XCD-local bh grouping
    int q0 = ((g >> 3) & 3) * 256 + w * 64;  // 64 q-rows per wave

    // K rows (A-frag): row = key0+col, k = s*16 + hi*8 + j
    const u16* kb = k_s + ((((size_t)bh << 10) + col) << 5) + hi * 8;
    // V fragment-order: group g16 -> 64 lanes x 8 u16, dense 1 KB per load
    const u16* vb = vt + ((size_t)bh << 15) + lane * 8;

    F4U qf[2][2];   // B-frags: Q[q=col][d = s*16 + hi*8 + j] for 2 q-tiles
    #pragma unroll
    for (int t = 0; t < 2; ++t)
        #pragma unroll
        for (int s = 0; s < 2; ++s)
            qf[t][s].u = *(const uint4*)(q_s + ((((size_t)bh << 10) + q0 + t * 32 + col) << 5) + s * 16 + hi * 8);

    f16f Z;                                  // persistent zero C-in for QK MFMA
    #pragma unroll
    for (int r = 0; r < 16; ++r) Z[r] = 0.f;

    f16f O[2];
    #pragma unroll
    for (int t = 0; t < 2; ++t)
        #pragma unroll
        for (int r = 0; r < 16; ++r) O[t][r] = 0.f;
    float psum[2] = {0.f, 0.f};

    F4U kA[2][2], kB[2][2], vA[2][2], vB[2][2];   // [key-half h][frag s]
    auto LD = [&](F4U (&kf)[2][2], F4U (&vf)[2][2], int key0) {
        int g16 = key0 >> 4;                       // base 16-key group
        #pragma unroll
        for (int h = 0; h < 2; ++h)
            #pragma unroll
            for (int s = 0; s < 2; ++s) {
                kf[h][s].u = *(const uint4*)(kb + (size_t)(key0 + h * 32) * 32 + s * 16);
                vf[h][s].u = *(const uint4*)(vb + (size_t)(g16 + h * 2 + s) * 512);
            }
    };
    auto STEP = [&](F4U (&kf)[2][2], F4U (&vf)[2][2]) {
        // phase 1: 8 independent QK MFMAs (4 chains of 2)
        f16f S[2][2];
        __builtin_amdgcn_s_setprio(1);
        #pragma unroll
        for (int t = 0; t < 2; ++t)
            #pragma unroll
            for (int h = 0; h < 2; ++h) {
                S[t][h] = __builtin_amdgcn_mfma_f32_32x32x16_bf16(kf[h][0].s, qf[t][0].s, Z, 0, 0, 0);
                S[t][h] = __builtin_amdgcn_mfma_f32_32x32x16_bf16(kf[h][1].s, qf[t][1].s, S[t][h], 0, 0, 0);
            }
        __builtin_amdgcn_s_setprio(0);
        // phase 2: 4 independent softmax+pack chains, natural order (no pswap)
        F4U pf[2][2][2];
        #pragma unroll
        for (int t = 0; t < 2; ++t)
            #pragma unroll
            for (int h = 0; h < 2; ++h) {
                float p[16];
                #pragma unroll
                for (int r = 0; r < 16; ++r) p[r] = __builtin_amdgcn_exp2f(S[t][h][r]);
                psum[t] += ((((p[0] + p[1]) + (p[2] + p[3])) + ((p[4] + p[5]) + (p[6] + p[7])))
                          + (((p[8] + p[9]) + (p[10] + p[11])) + ((p[12] + p[13]) + (p[14] + p[15]))));
                pf[t][h][0].u = make_uint4(cvt_pk_bf16(p[0],  p[1]),  cvt_pk_bf16(p[2],  p[3]),
                                           cvt_pk_bf16(p[4],  p[5]),  cvt_pk_bf16(p[6],  p[7]));
                pf[t][h][1].u = make_uint4(cvt_pk_bf16(p[8],  p[9]),  cvt_pk_bf16(p[10], p[11]),
                                           cvt_pk_bf16(p[12], p[13]), cvt_pk_bf16(p[14], p[15]));
            }
        // phase 3: 8 PV MFMAs (2 independent O-chains)
        __builtin_amdgcn_s_setprio(1);
        #pragma unroll
        for (int t = 0; t < 2; ++t) {
            O[t] = __builtin_amdgcn_mfma_f32_32x32x16_bf16(vf[0][0].s, pf[t][0][0].s, O[t], 0, 0, 0);
            O[t] = __builtin_amdgcn_mfma_f32_32x32x16_bf16(vf[0][1].s, pf[t][0][1].s, O[t], 0, 0, 0);
            O[t] = __builtin_amdgcn_mfma_f32_32x32x16_bf16(vf[1][0].s, pf[t][1][0].s, O[t], 0, 0, 0);
            O[t] = __builtin_amdgcn_mfma_f32_32x32x16_bf16(vf[1][1].s, pf[t][1][1].s, O[t], 0, 0, 0);
        }
        __builtin_amdgcn_s_setprio(0);
    };

    LD(kA, vA, 0);
    for (int u = 0; u < 16; u += 2) {            // 16 units of 64 keys
        LD(kB, vB, (u + 1) * 64);
        STEP(kA, vA);
        if (u + 2 < 16) LD(kA, vA, (u + 2) * 64);
        STEP(kB, vB);
    }

    #pragma unroll
    for (int t = 0; t < 2; ++t) {
        float ps = psum[t];
        ps += __shfl_xor(ps, 32);              // other hi-half holds other keys
        float inv = 1.0f / ps;
        // O C-layout: col = q, row = d = (r&3) + 8*(r>>2) + 4*hi
        u16* op = ctx + ((((size_t)bh << 10) + q0 + t * 32 + col) << 5) + hi * 4;
        #pragma unroll
        for (int gi = 0; gi < 4; ++gi) {
            uint2 st;
            st.x = cvt_pk_bf16(O[t][4 * gi + 0] * inv, O[t][4 * gi + 1] * inv);
            st.y = cvt_pk_bf16(O[t][4 * gi + 2] * inv, O[t][4 * gi + 3] * inv);
            *(uint2*)(op + gi * 8) = st;
        }
    }
}

// ---- kernel 4: out = LN(ctx @ Wout^T + out_b + emb) -> fp32, fused.
// R13 version: 32 rows/block (512 blocks), 2 m-tiles per wave sharing every
// B-frag; wout fragment-order (dense B); residual via seq-indirected tbl.
__global__ __launch_bounds__(256) void proj_ln_k(
    const int* __restrict__ seq,      // [M]
    const u16* __restrict__ ctx,      // [bh][l][32] bf16
    const u16* __restrict__ wout,     // [16][8][16][32] bf16 fragment-order
    const float* __restrict__ out_b,  // [256]
    const u16* __restrict__ tbl,      // [L,4,256] bf16
    float* __restrict__ out)          // [M,256] fp32
{
    __shared__ float2 sm[4][2][16];   // [wave][tile][l15(row)]
    int tid = threadIdx.x;
    int w = tid >> 6, lane = tid & 63, l15 = lane & 15, quad = lane >> 4;
    int m0 = blockIdx.x * 32;
    int b = m0 >> 10;

    // fragment-order B: dense 1 KB per (nb, ks) wave-load
    const u16* Bp = wout + (size_t)(w * 4) * 4096 + l15 * 32 + quad * 8;

    f4_t acc[2][4] = {{{0,0,0,0},{0,0,0,0},{0,0,0,0},{0,0,0,0}},
                      {{0,0,0,0},{0,0,0,0},{0,0,0,0},{0,0,0,0}}};

    #pragma unroll
    for (int ks = 0; ks < 8; ++ks) {      // k = ks*32 + quad*8+j (head ks)
        F4U bf[4];
        #pragma unroll
        for (int nc = 0; nc < 4; ++nc)
            bf[nc].u = *(const uint4*)(Bp + nc * 4096 + ks * 512);
        #pragma unroll
        for (int t = 0; t < 2; ++t) {
            int lbase = (m0 & 1023) + t * 16 + l15;
            F4U a; a.u = *(const uint4*)(ctx + ((size_t)(b * 8 + ks) * 1024 + lbase) * 32 + quad * 8);
            #pragma unroll
            for (int nc = 0; nc < 4; ++nc)
                acc[t][nc] = __builtin_amdgcn_mfma_f32_16x16x32_bf16(bf[nc].s, a.s, acc[t][nc], 0, 0, 0);
        }
    }

    #pragma unroll
    for (int t = 0; t < 2; ++t) {
        int row = m0 + t * 16 + l15;
        int cls = seq[row];
        const u16* ep = tbl + ((size_t)((row & 1023) * 4 + cls)) * 256;
        float s = 0.f, q = 0.f;
        #pragma unroll
        for (int nc = 0; nc < 4; ++nc) {
            int nb = w * 64 + nc * 16 + quad * 4;
            float4 bb = *(const float4*)(out_b + nb);
            ushort4 e4 = *(const ushort4*)(ep + nb);
            acc[t][nc][0] += bb.x + bf2f(e4.x);
            acc[t][nc][1] += bb.y + bf2f(e4.y);
            acc[t][nc][2] += bb.z + bf2f(e4.z);
            acc[t][nc][3] += bb.w + bf2f(e4.w);
            #pragma unroll
            for (int r = 0; r < 4; ++r) { s += acc[t][nc][r]; q += acc[t][nc][r] * acc[t][nc][r]; }
        }
        s += __shfl_xor(s, 16);  q += __shfl_xor(q, 16);
        s += __shfl_xor(s, 32);  q += __shfl_xor(q, 32);
        if (quad == 0) sm[w][t][l15] = make_float2(s, q);
    }
    __syncthreads();
    #pragma unroll
    for (int t = 0; t < 2; ++t) {
        int row = m0 + t * 16 + l15;
        float2 t0 = sm[0][t][l15], t1 = sm[1][t][l15], t2 = sm[2][t][l15], t3 = sm[3][t][l15];
        float s = (t0.x + t1.x) + (t2.x + t3.x);
        float q = (t0.y + t1.y) + (t2.y + t3.y);
        float mean = s * (1.0f / 256.0f);
        float var  = q * (1.0f / 256.0f) - mean * mean;
        float rstd = rsqrtf(var + 1e-5f);
        #pragma unroll
        for (int nc = 0; nc < 4; ++nc) {
            float4 o = { (acc[t][nc][0] - mean) * rstd, (acc[t][nc][1] - mean) * rstd,
                         (acc[t][nc][2] - mean) * rstd, (acc[t][nc][3] - mean) * rstd };
            *(float4*)(out + (size_t)row * 256 + w * 64 + nc * 16 + quad * 4) = o;
        }
    }
}

extern "C" void kernel_launch(void* const* d_in, const int* in_sizes, int n_in,
                              void* d_out, int out_size, void* d_ws, size_t ws_size,
                              hipStream_t stream) {
    const int*   seq       = (const int*)d_in[0];
    const float* emb_w     = (const float*)d_in[1];
    const float* emb_b     = (const float*)d_in[2];
    const float* in_proj_w = (const float*)d_in[3];
    const float* in_proj_b = (const float*)d_in[4];
    const float* out_w     = (const float*)d_in[5];
    const float* out_b     = (const float*)d_in[6];
    float*       out       = (float*)d_out;

    const size_t P   = (size_t)M_ * 256;     // 4,194,304 els
    const size_t TBL = (size_t)L_ * 4 * 256; // 1,048,576 els (2 MB)
    u16* ws   = (u16*)d_ws;
    u16* tbl  = ws;                  //  2 MB [L,4,256]
    u16* q_s  = ws + TBL;            //  8 MB [bh][l][32]
    u16* k_s  = q_s + P;             //  8 MB [bh][l][32]
    u16* vt   = k_s + P;             //  8 MB [bh][64][64][8] fragment-order
    u16* ctx  = vt + P;              //  8 MB [bh][l][32]
    u16* wqkv = ctx + P;             //  384 KB fragment-order
    u16* wout = wqkv + 768 * 256;    //  128 KB fragment-order
    // af ALIASES ctx: af is dead after gemm; attn fully overwrites ctx after.
    u16* af   = ctx;                 //  8 MB [M/16][8][16][32] fragment-order

    table_conv_k<<<1024, 256, 0, stream>>>(emb_w, emb_b, in_proj_w, out_w, tbl, wqkv);
    gather_a_k<<<2048, 256, 0, stream>>>(seq, tbl, af);
    gemm_qkv_mfma_k<<<dim3(12, 64), 256, 0, stream>>>(af, wqkv, in_proj_b, q_s, k_s, vt);
    attn32_k<<<512, 256, 0, stream>>>(q_s, k_s, vt, ctx);
    proj_ln_k<<<M_ / 32, 256, 0, stream>>>(seq, ctx, wout, out_b, tbl, out);
}

// Round 16
// 144.722 us; speedup vs baseline: 1.0225x; 1.0225x over previous
//
#include <hip/hip_runtime.h>

#define B_  16
#define L_  1024
#define E_  256
#define H_  8
#define DH_ 32
#define M_  (B_ * L_)                 // 16384 rows
#define SCALE_L2E 0.25501817656f      // (1/sqrt(32)) * log2(e)

typedef unsigned short u16;
typedef unsigned int   u32;
typedef short bf8_t __attribute__((ext_vector_type(8)));   // 8 bf16 (4 VGPRs)
typedef float f4_t  __attribute__((ext_vector_type(4)));   // MFMA acc 16x16
typedef float f16f  __attribute__((ext_vector_type(16)));  // MFMA acc 32x32
union F4U { uint4 u; bf8_t s; };

static __device__ __forceinline__ float bf2f(u16 u) {
    return __uint_as_float(((u32)u) << 16);
}
static __device__ __forceinline__ u16 f2bf(float f) {
    u32 u = __float_as_uint(f);
    u32 r = 0x7FFFu + ((u >> 16) & 1u);   // RNE
    return (u16)((u + r) >> 16);
}
// hardware packed f32->bf16x2 convert (RNE), 1 VALU op
static __device__ __forceinline__ u32 cvt_pk_bf16(float a, float b) {
    u32 r;
    asm("v_cvt_pk_bf16_f32 %0, %1, %2" : "=v"(r) : "v"(a), "v"(b));
    return r;
}

// ---- kernel 1: LN'd embedding TABLE (l x class, 4096 rows) + W->bf16 convert.
// weights stored in MFMA-FRAGMENT order w_f[n>>4][k>>5][n&15][k&31] (R13).
__global__ __launch_bounds__(256) void table_conv_k(
    const float* __restrict__ emb_w,      // [L,E,4] fp32
    const float* __restrict__ emb_b,      // [L,E]
    const float* __restrict__ in_proj_w,  // [768,256] fp32
    const float* __restrict__ out_w,      // [256,256] fp32
    u16* __restrict__ tbl,                // [L,4,E] bf16 (LN'd)
    u16* __restrict__ wcvt)               // [768*256 + 256*256] bf16 fragment-order
{
    __shared__ float sm[256][5];          // [element e][class c], pad 5
    int blk = blockIdx.x, tid = threadIdx.x;
    {   // weight conversion -> fragment order: 1024 blocks x 256 threads
        int idx = blk * 256 + tid;
        float v = (idx < 196608) ? in_proj_w[idx] : out_w[idx - 196608];
        int base = (idx < 196608) ? 0 : 196608;
        int rel = idx - base;
        int n = rel >> 8, k = rel & 255;
        wcvt[base + ((n >> 4) * 4096 + (k >> 5) * 512 + (n & 15) * 32 + (k & 31))] = f2bf(v);
    }
    int w = tid >> 6, lane = tid & 63;
    int l = blk;
    {   // coalesced: thread tid loads all 4 classes of element e=tid
        float4 v = *(const float4*)(emb_w + (size_t)l * 1024 + tid * 4);
        sm[tid][0] = v.x; sm[tid][1] = v.y; sm[tid][2] = v.z; sm[tid][3] = v.w;
    }
    __syncthreads();
    float4 bb = *(const float4*)(emb_b + (size_t)l * 256 + lane * 4);
    float bv[4] = {bb.x, bb.y, bb.z, bb.w};
    float x[4], s = 0.f, q = 0.f;
    #pragma unroll
    for (int j = 0; j < 4; ++j) {
        float t = sm[lane * 4 + j][w] + bv[j];   // class w of element lane*4+j
        x[j] = t; s += t; q += t * t;
    }
    #pragma unroll
    for (int off = 1; off < 64; off <<= 1) {
        s += __shfl_xor(s, off);
        q += __shfl_xor(q, off);
    }
    float mean = s * (1.0f / 256.0f);
    float var  = q * (1.0f / 256.0f) - mean * mean;
    float rstd = rsqrtf(var + 1e-5f);
    ushort4 o = { f2bf((x[0] - mean) * rstd), f2bf((x[1] - mean) * rstd),
                  f2bf((x[2] - mean) * rstd), f2bf((x[3] - mean) * rstd) };
    *(ushort4*)(tbl + ((size_t)l * 4 + w) * 256 + lane * 4) = o;
}

// ---- kernel 2: QKV = emb @ Wqkv^T + b (MFMA, LDS-free), 4 m-tiles per wave.
// B loads 1 KB fully-coalesced (fragment-order wqkv from kernel 1).
// A loads seq-indirected gathers (L2-resident tbl). V stored in fragment
// order vt[bh][g][lane][8] with bit-2/3 key swap (R12, proven).
__global__ __launch_bounds__(256, 2) void gemm_qkv_mfma_k(
    const int* __restrict__ seq,      // [M]
    const u16* __restrict__ tbl,      // [L,4,256] bf16
    const u16* __restrict__ wqkv,     // [48][8][16][32] bf16 fragment-order
    const float* __restrict__ bias,   // [768] fp32
    u16* __restrict__ q_s, u16* __restrict__ k_s, u16* __restrict__ vt)
{
    int tid = threadIdx.x;
    int w = tid >> 6, lane = tid & 63, l15 = lane & 15, quad = lane >> 4;
    int n0 = blockIdx.x * 64, m0 = blockIdx.y * 256;
    int b = m0 >> 10;

    const u16* Apt[4];
    #pragma unroll
    for (int t = 0; t < 4; ++t) {
        int m = m0 + w * 64 + t * 16 + l15;
        int cls = seq[m];
        Apt[t] = tbl + ((size_t)((m & 1023) * 4 + cls)) * 256 + quad * 8;
    }
    // fragment-order B: dense 1 KB per (nb, ks) wave-load
    const u16* Bp = wqkv + (size_t)(n0 >> 4) * 4096 + l15 * 32 + quad * 8;

    f4_t acc[4][4] = {{{0,0,0,0},{0,0,0,0},{0,0,0,0},{0,0,0,0}},
                      {{0,0,0,0},{0,0,0,0},{0,0,0,0},{0,0,0,0}},
                      {{0,0,0,0},{0,0,0,0},{0,0,0,0},{0,0,0,0}},
                      {{0,0,0,0},{0,0,0,0},{0,0,0,0},{0,0,0,0}}};

    if (n0 < 512) {                        // ---- Q or K: transposed C ----
        #pragma unroll
        for (int ks = 0; ks < 8; ++ks) {
            F4U bfr[4];
            #pragma unroll
            for (int nc = 0; nc < 4; ++nc)
                bfr[nc].u = *(const uint4*)(Bp + nc * 4096 + ks * 512);
            #pragma unroll
            for (int t = 0; t < 4; ++t) {
                F4U a; a.u = *(const uint4*)(Apt[t] + ks * 32);
                #pragma unroll
                for (int nc = 0; nc < 4; ++nc)
                    acc[t][nc] = __builtin_amdgcn_mfma_f32_16x16x32_bf16(bfr[nc].s, a.s, acc[t][nc], 0, 0, 0);
            }
        }
        float sc = (n0 < 256) ? SCALE_L2E : 1.0f;
        u16* dst = (n0 < 256) ? q_s : k_s;
        #pragma unroll
        for (int t = 0; t < 4; ++t) {
            int l = (m0 & 1023) + w * 64 + t * 16 + l15;
            #pragma unroll
            for (int nc = 0; nc < 4; ++nc) {
                int nb = n0 + nc * 16 + quad * 4;  // 4 consecutive n = same head
                float4 b4 = *(const float4*)(bias + nb);
                int nl = nb & 255, h = nl >> 5, d0 = nl & 31;
                ushort4 o = { f2bf((acc[t][nc][0] + b4.x) * sc), f2bf((acc[t][nc][1] + b4.y) * sc),
                              f2bf((acc[t][nc][2] + b4.z) * sc), f2bf((acc[t][nc][3] + b4.w) * sc) };
                *(ushort4*)(dst + ((size_t)(b * 8 + h) * 1024 + l) * 32 + d0) = o;
            }
        }
    } else {                               // ---- V: normal C, store fragment-order ----
        #pragma unroll
        for (int ks = 0; ks < 8; ++ks) {
            F4U bfr[4];
            #pragma unroll
            for (int nc = 0; nc < 4; ++nc)
                bfr[nc].u = *(const uint4*)(Bp + nc * 4096 + ks * 512);
            #pragma unroll
            for (int t = 0; t < 4; ++t) {
                F4U a; a.u = *(const uint4*)(Apt[t] + ks * 32);
                #pragma unroll
                for (int nc = 0; nc < 4; ++nc)
                    acc[t][nc] = __builtin_amdgcn_mfma_f32_16x16x32_bf16(a.s, bfr[nc].s, acc[t][nc], 0, 0, 0);
            }
        }
        #pragma unroll
        for (int t = 0; t < 4; ++t) {
            int lq = (m0 & 1023) + w * 64 + t * 16 + quad * 4;  // 4-aligned key base
            // stored position: bit-2/3 swap of within-group key index
            int lqp = (lq & ~12) | ((lq & 4) << 1) | ((lq & 8) >> 1);
            int g  = lq >> 4;          // 16-key group (0..63)
            int q0 = lqp & 15;         // in {0,4,8,12}
            #pragma unroll
            for (int nc = 0; nc < 4; ++nc) {
                int n = n0 + nc * 16 + l15;
                float bv = bias[n];
                int nl = n & 255, h = nl >> 5, d = nl & 31;
                ushort4 o = { f2bf(acc[t][nc][0] + bv), f2bf(acc[t][nc][1] + bv),
                              f2bf(acc[t][nc][2] + bv), f2bf(acc[t][nc][3] + bv) };
                // vt2[bh][g][lane = d + 32*(q0>>3)][8] ; 4 u16 at +(q0&7)
                *(ushort4*)(vt + (((size_t)(b * 8 + h) * 64 + g) * 64 + d + ((q0 >> 3) << 5)) * 8 + (q0 & 7)) = o;
            }
        }
    }
}

// ---- kernel 3: MFMA flash attention (R12 — proven best, fragment-order V).
// 512 blocks, 4 waves, 64 q-rows/wave, 64-key units, no LDS, K/V ping-pong.
// V loads 1 KB fully-coalesced; K loads dense. EXPPACK straight-line.
__global__ __launch_bounds__(256, 2) void attn32_k(
    const u16* __restrict__ q_s,   // [bh][l][32] (pre-scaled by SCALE*log2e)
    const u16* __restrict__ k_s,   // [bh][l][32]
    const u16* __restrict__ vt,    // [bh][64][64][8] fragment-order
    u16* __restrict__ ctx)         // [bh][l][32]
{
    int tid = threadIdx.x;
    int w = tid >> 6, lane = tid & 63, col = lane & 31, hi = lane >> 5;
    int g = blockIdx.x;                      // 512 blocks = 4 qt x 128 bh
    int bh = (g & 7) | ((g >> 5) << 3);      // XCD-local bh grouping
    int q0 = ((g >> 3) & 3) * 256 + w * 64;  // 64 q-rows per wave

    // K rows (A-frag): row = key0+col, k = s*16 + hi*8 + j
    const u16* kb = k_s + ((((size_t)bh << 10) + col) << 5) + hi * 8;
    // V fragment-order: group g16 -> 64 lanes x 8 u16, dense 1 KB per load
    const u16* vb = vt + ((size_t)bh << 15) + lane * 8;

    F4U qf[2][2];   // B-frags: Q[q=col][d = s*16 + hi*8 + j] for 2 q-tiles
    #pragma unroll
    for (int t = 0; t < 2; ++t)
        #pragma unroll
        for (int s = 0; s < 2; ++s)
            qf[t][s].u = *(const uint4*)(q_s + ((((size_t)bh << 10) + q0 + t * 32 + col) << 5) + s * 16 + hi * 8);

    f16f Z;                                  // persistent zero C-in for QK MFMA
    #pragma unroll
    for (int r = 0; r < 16; ++r) Z[r] = 0.f;

    f16f O[2];
    #pragma unroll
    for (int t = 0; t < 2; ++t)
        #pragma unroll
        for (int r = 0; r < 16; ++r) O[t][r] = 0.f;
    float psum[2] = {0.f, 0.f};

    F4U kA[2][2], kB[2][2], vA[2][2], vB[2][2];   // [key-half h][frag s]
    auto LD = [&](F4U (&kf)[2][2], F4U (&vf)[2][2], int key0) {
        int g16 = key0 >> 4;                       // base 16-key group
        #pragma unroll
        for (int h = 0; h < 2; ++h)
            #pragma unroll
            for (int s = 0; s < 2; ++s) {
                kf[h][s].u = *(const uint4*)(kb + (size_t)(key0 + h * 32) * 32 + s * 16);
                vf[h][s].u = *(const uint4*)(vb + (size_t)(g16 + h * 2 + s) * 512);
            }
    };
    auto STEP = [&](F4U (&kf)[2][2], F4U (&vf)[2][2]) {
        // phase 1: 8 independent QK MFMAs (4 chains of 2)
        f16f S[2][2];
        __builtin_amdgcn_s_setprio(1);
        #pragma unroll
        for (int t = 0; t < 2; ++t)
            #pragma unroll
            for (int h = 0; h < 2; ++h) {
                S[t][h] = __builtin_amdgcn_mfma_f32_32x32x16_bf16(kf[h][0].s, qf[t][0].s, Z, 0, 0, 0);
                S[t][h] = __builtin_amdgcn_mfma_f32_32x32x16_bf16(kf[h][1].s, qf[t][1].s, S[t][h], 0, 0, 0);
            }
        __builtin_amdgcn_s_setprio(0);
        // phase 2: 4 independent softmax+pack chains, natural order (no pswap)
        F4U pf[2][2][2];
        #pragma unroll
        for (int t = 0; t < 2; ++t)
            #pragma unroll
            for (int h = 0; h < 2; ++h) {
                float p[16];
                #pragma unroll
                for (int r = 0; r < 16; ++r) p[r] = __builtin_amdgcn_exp2f(S[t][h][r]);
                psum[t] += ((((p[0] + p[1]) + (p[2] + p[3])) + ((p[4] + p[5]) + (p[6] + p[7])))
                          + (((p[8] + p[9]) + (p[10] + p[11])) + ((p[12] + p[13]) + (p[14] + p[15]))));
                pf[t][h][0].u = make_uint4(cvt_pk_bf16(p[0],  p[1]),  cvt_pk_bf16(p[2],  p[3]),
                                           cvt_pk_bf16(p[4],  p[5]),  cvt_pk_bf16(p[6],  p[7]));
                pf[t][h][1].u = make_uint4(cvt_pk_bf16(p[8],  p[9]),  cvt_pk_bf16(p[10], p[11]),
                                           cvt_pk_bf16(p[12], p[13]), cvt_pk_bf16(p[14], p[15]));
            }
        // phase 3: 8 PV MFMAs (2 independent O-chains)
        __builtin_amdgcn_s_setprio(1);
        #pragma unroll
        for (int t = 0; t < 2; ++t) {
            O[t] = __builtin_amdgcn_mfma_f32_32x32x16_bf16(vf[0][0].s, pf[t][0][0].s, O[t], 0, 0, 0);
            O[t] = __builtin_amdgcn_mfma_f32_32x32x16_bf16(vf[0][1].s, pf[t][0][1].s, O[t], 0, 0, 0);
            O[t] = __builtin_amdgcn_mfma_f32_32x32x16_bf16(vf[1][0].s, pf[t][1][0].s, O[t], 0, 0, 0);
            O[t] = __builtin_amdgcn_mfma_f32_32x32x16_bf16(vf[1][1].s, pf[t][1][1].s, O[t], 0, 0, 0);
        }
        __builtin_amdgcn_s_setprio(0);
    };

    LD(kA, vA, 0);
    for (int u = 0; u < 16; u += 2) {            // 16 units of 64 keys
        LD(kB, vB, (u + 1) * 64);
        STEP(kA, vA);
        if (u + 2 < 16) LD(kA, vA, (u + 2) * 64);
        STEP(kB, vB);
    }

    #pragma unroll
    for (int t = 0; t < 2; ++t) {
        float ps = psum[t];
        ps += __shfl_xor(ps, 32);              // other hi-half holds other keys
        float inv = 1.0f / ps;
        // O C-layout: col = q, row = d = (r&3) + 8*(r>>2) + 4*hi
        u16* op = ctx + ((((size_t)bh << 10) + q0 + t * 32 + col) << 5) + hi * 4;
        #pragma unroll
        for (int gi = 0; gi < 4; ++gi) {
            uint2 st;
            st.x = cvt_pk_bf16(O[t][4 * gi + 0] * inv, O[t][4 * gi + 1] * inv);
            st.y = cvt_pk_bf16(O[t][4 * gi + 2] * inv, O[t][4 * gi + 3] * inv);
            *(uint2*)(op + gi * 8) = st;
        }
    }
}

// ---- kernel 4: out = LN(ctx @ Wout^T + out_b + emb) -> fp32, fused.
// 32 rows/block (512 blocks), 2 m-tiles per wave sharing every B-frag.
// wout in fragment order -> B loads 1 KB fully-coalesced.
__global__ __launch_bounds__(256) void proj_ln_k(
    const int* __restrict__ seq,      // [M]
    const u16* __restrict__ ctx,      // [bh][l][32] bf16
    const u16* __restrict__ wout,     // [16][8][16][32] bf16 fragment-order
    const float* __restrict__ out_b,  // [256]
    const u16* __restrict__ tbl,      // [L,4,256] bf16
    float* __restrict__ out)          // [M,256] fp32
{
    __shared__ float2 sm[4][2][16];   // [wave][tile][l15(row)]
    int tid = threadIdx.x;
    int w = tid >> 6, lane = tid & 63, l15 = lane & 15, quad = lane >> 4;
    int m0 = blockIdx.x * 32;
    int b = m0 >> 10;

    // fragment-order B: dense 1 KB per (nb, ks) wave-load
    const u16* Bp = wout + (size_t)(w * 4) * 4096 + l15 * 32 + quad * 8;

    f4_t acc[2][4] = {{{0,0,0,0},{0,0,0,0},{0,0,0,0},{0,0,0,0}},
                      {{0,0,0,0},{0,0,0,0},{0,0,0,0},{0,0,0,0}}};

    #pragma unroll
    for (int ks = 0; ks < 8; ++ks) {      // k = ks*32 + quad*8+j (head ks)
        F4U bf[4];
        #pragma unroll
        for (int nc = 0; nc < 4; ++nc)
            bf[nc].u = *(const uint4*)(Bp + nc * 4096 + ks * 512);
        #pragma unroll
        for (int t = 0; t < 2; ++t) {
            int lbase = (m0 & 1023) + t * 16 + l15;
            F4U a; a.u = *(const uint4*)(ctx + ((size_t)(b * 8 + ks) * 1024 + lbase) * 32 + quad * 8);
            #pragma unroll
            for (int nc = 0; nc < 4; ++nc)
                acc[t][nc] = __builtin_amdgcn_mfma_f32_16x16x32_bf16(bf[nc].s, a.s, acc[t][nc], 0, 0, 0);
        }
    }

    #pragma unroll
    for (int t = 0; t < 2; ++t) {
        int row = m0 + t * 16 + l15;
        int cls = seq[row];
        const u16* ep = tbl + ((size_t)((row & 1023) * 4 + cls)) * 256;
        float s = 0.f, q = 0.f;
        #pragma unroll
        for (int nc = 0; nc < 4; ++nc) {
            int nb = w * 64 + nc * 16 + quad * 4;
            float4 bb = *(const float4*)(out_b + nb);
            ushort4 e4 = *(const ushort4*)(ep + nb);
            acc[t][nc][0] += bb.x + bf2f(e4.x);
            acc[t][nc][1] += bb.y + bf2f(e4.y);
            acc[t][nc][2] += bb.z + bf2f(e4.z);
            acc[t][nc][3] += bb.w + bf2f(e4.w);
            #pragma unroll
            for (int r = 0; r < 4; ++r) { s += acc[t][nc][r]; q += acc[t][nc][r] * acc[t][nc][r]; }
        }
        s += __shfl_xor(s, 16);  q += __shfl_xor(q, 16);
        s += __shfl_xor(s, 32);  q += __shfl_xor(q, 32);
        if (quad == 0) sm[w][t][l15] = make_float2(s, q);
    }
    __syncthreads();
    #pragma unroll
    for (int t = 0; t < 2; ++t) {
        int row = m0 + t * 16 + l15;
        float2 t0 = sm[0][t][l15], t1 = sm[1][t][l15], t2 = sm[2][t][l15], t3 = sm[3][t][l15];
        float s = (t0.x + t1.x) + (t2.x + t3.x);
        float q = (t0.y + t1.y) + (t2.y + t3.y);
        float mean = s * (1.0f / 256.0f);
        float var  = q * (1.0f / 256.0f) - mean * mean;
        float rstd = rsqrtf(var + 1e-5f);
        #pragma unroll
        for (int nc = 0; nc < 4; ++nc) {
            float4 o = { (acc[t][nc][0] - mean) * rstd, (acc[t][nc][1] - mean) * rstd,
                         (acc[t][nc][2] - mean) * rstd, (acc[t][nc][3] - mean) * rstd };
            *(float4*)(out + (size_t)row * 256 + w * 64 + nc * 16 + quad * 4) = o;
        }
    }
}

extern "C" void kernel_launch(void* const* d_in, const int* in_sizes, int n_in,
                              void* d_out, int out_size, void* d_ws, size_t ws_size,
                              hipStream_t stream) {
    const int*   seq       = (const int*)d_in[0];
    const float* emb_w     = (const float*)d_in[1];
    const float* emb_b     = (const float*)d_in[2];
    const float* in_proj_w = (const float*)d_in[3];
    const float* in_proj_b = (const float*)d_in[4];
    const float* out_w     = (const float*)d_in[5];
    const float* out_b     = (const float*)d_in[6];
    float*       out       = (float*)d_out;

    const size_t P   = (size_t)M_ * 256;     // 4,194,304 els
    const size_t TBL = (size_t)L_ * 4 * 256; // 1,048,576 els (2 MB)
    u16* ws   = (u16*)d_ws;
    u16* tbl  = ws;                  //  2 MB [L,4,256]
    u16* q_s  = ws + TBL;            //  8 MB [bh][l][32]
    u16* k_s  = q_s + P;             //  8 MB [bh][l][32]
    u16* vt   = k_s + P;             //  8 MB [bh][64][64][8] fragment-order
    u16* ctx  = vt + P;              //  8 MB [bh][l][32]
    u16* wqkv = ctx + P;             //  384 KB fragment-order
    u16* wout = wqkv + 768 * 256;    //  128 KB fragment-order

    table_conv_k<<<1024, 256, 0, stream>>>(emb_w, emb_b, in_proj_w, out_w, tbl, wqkv);
    gemm_qkv_mfma_k<<<dim3(12, 64), 256, 0, stream>>>(seq, tbl, wqkv, in_proj_b, q_s, k_s, vt);
    attn32_k<<<512, 256, 0, stream>>>(q_s, k_s, vt, ctx);
    proj_ln_k<<<M_ / 32, 256, 0, stream>>>(seq, ctx, wout, out_b, tbl, out);
}

// Round 17
// 134.542 us; speedup vs baseline: 1.0998x; 1.0757x over previous
//
#include <hip/hip_runtime.h>

#define B_  16
#define L_  1024
#define E_  256
#define H_  8
#define DH_ 32
#define M_  (B_ * L_)                 // 16384 rows
#define SCALE_L2E 0.25501817656f      // (1/sqrt(32)) * log2(e)

typedef unsigned short u16;
typedef unsigned int   u32;
typedef short bf8_t __attribute__((ext_vector_type(8)));   // 8 bf16 (4 VGPRs)
typedef float f4_t  __attribute__((ext_vector_type(4)));   // MFMA acc 16x16
typedef float f16f  __attribute__((ext_vector_type(16)));  // MFMA acc 32x32
union F4U { uint4 u; bf8_t s; };

static __device__ __forceinline__ float bf2f(u16 u) {
    return __uint_as_float(((u32)u) << 16);
}
static __device__ __forceinline__ u16 f2bf(float f) {
    u32 u = __float_as_uint(f);
    u32 r = 0x7FFFu + ((u >> 16) & 1u);   // RNE
    return (u16)((u + r) >> 16);
}
// hardware packed f32->bf16x2 convert (RNE), 1 VALU op
static __device__ __forceinline__ u32 cvt_pk_bf16(float a, float b) {
    u32 r;
    asm("v_cvt_pk_bf16_f32 %0, %1, %2" : "=v"(r) : "v"(a), "v"(b));
    return r;
}

// ---- kernel 1: LN'd embedding TABLE (l x class, 4096 rows) + W->bf16 convert.
// weights stored in MFMA-FRAGMENT order w_f[n>>4][k>>5][n&15][k&31] (R13).
__global__ __launch_bounds__(256) void table_conv_k(
    const float* __restrict__ emb_w,      // [L,E,4] fp32
    const float* __restrict__ emb_b,      // [L,E]
    const float* __restrict__ in_proj_w,  // [768,256] fp32
    const float* __restrict__ out_w,      // [256,256] fp32
    u16* __restrict__ tbl,                // [L,4,E] bf16 (LN'd)
    u16* __restrict__ wcvt)               // [768*256 + 256*256] bf16 fragment-order
{
    __shared__ float sm[256][5];          // [element e][class c], pad 5
    int blk = blockIdx.x, tid = threadIdx.x;
    {   // weight conversion -> fragment order: 1024 blocks x 256 threads
        int idx = blk * 256 + tid;
        float v = (idx < 196608) ? in_proj_w[idx] : out_w[idx - 196608];
        int base = (idx < 196608) ? 0 : 196608;
        int rel = idx - base;
        int n = rel >> 8, k = rel & 255;
        wcvt[base + ((n >> 4) * 4096 + (k >> 5) * 512 + (n & 15) * 32 + (k & 31))] = f2bf(v);
    }
    int w = tid >> 6, lane = tid & 63;
    int l = blk;
    {   // coalesced: thread tid loads all 4 classes of element e=tid
        float4 v = *(const float4*)(emb_w + (size_t)l * 1024 + tid * 4);
        sm[tid][0] = v.x; sm[tid][1] = v.y; sm[tid][2] = v.z; sm[tid][3] = v.w;
    }
    __syncthreads();
    float4 bb = *(const float4*)(emb_b + (size_t)l * 256 + lane * 4);
    float bv[4] = {bb.x, bb.y, bb.z, bb.w};
    float x[4], s = 0.f, q = 0.f;
    #pragma unroll
    for (int j = 0; j < 4; ++j) {
        float t = sm[lane * 4 + j][w] + bv[j];   // class w of element lane*4+j
        x[j] = t; s += t; q += t * t;
    }
    #pragma unroll
    for (int off = 1; off < 64; off <<= 1) {
        s += __shfl_xor(s, off);
        q += __shfl_xor(q, off);
    }
    float mean = s * (1.0f / 256.0f);
    float var  = q * (1.0f / 256.0f) - mean * mean;
    float rstd = rsqrtf(var + 1e-5f);
    ushort4 o = { f2bf((x[0] - mean) * rstd), f2bf((x[1] - mean) * rstd),
                  f2bf((x[2] - mean) * rstd), f2bf((x[3] - mean) * rstd) };
    *(ushort4*)(tbl + ((size_t)l * 4 + w) * 256 + lane * 4) = o;
}

// ---- kernel 2: QKV = emb @ Wqkv^T + b (MFMA, LDS-free), 4 m-tiles per wave.
// v8: Q/K ALSO stored in fragment order qk_f[bh][g32=l>>5][s=d>>4]
// [lane'=(l&31)+32*((d>>3)&1)][j=d&7] so attn's Q/K loads are dense 1 KB
// (16 lines, was 32) and the stores here are two dense 256B regions (8
// lines, was 16). B dense (R13); V fragment-order w/ bit-2/3 swap (R12).
__global__ __launch_bounds__(256, 2) void gemm_qkv_mfma_k(
    const int* __restrict__ seq,      // [M]
    const u16* __restrict__ tbl,      // [L,4,256] bf16
    const u16* __restrict__ wqkv,     // [48][8][16][32] bf16 fragment-order
    const float* __restrict__ bias,   // [768] fp32
    u16* __restrict__ q_s, u16* __restrict__ k_s, u16* __restrict__ vt)
{
    int tid = threadIdx.x;
    int w = tid >> 6, lane = tid & 63, l15 = lane & 15, quad = lane >> 4;
    int n0 = blockIdx.x * 64, m0 = blockIdx.y * 256;
    int b = m0 >> 10;

    const u16* Apt[4];
    #pragma unroll
    for (int t = 0; t < 4; ++t) {
        int m = m0 + w * 64 + t * 16 + l15;
        int cls = seq[m];
        Apt[t] = tbl + ((size_t)((m & 1023) * 4 + cls)) * 256 + quad * 8;
    }
    // fragment-order B: dense 1 KB per (nb, ks) wave-load
    const u16* Bp = wqkv + (size_t)(n0 >> 4) * 4096 + l15 * 32 + quad * 8;

    f4_t acc[4][4] = {{{0,0,0,0},{0,0,0,0},{0,0,0,0},{0,0,0,0}},
                      {{0,0,0,0},{0,0,0,0},{0,0,0,0},{0,0,0,0}},
                      {{0,0,0,0},{0,0,0,0},{0,0,0,0},{0,0,0,0}},
                      {{0,0,0,0},{0,0,0,0},{0,0,0,0},{0,0,0,0}}};

    if (n0 < 512) {                        // ---- Q or K: transposed C ----
        #pragma unroll
        for (int ks = 0; ks < 8; ++ks) {
            F4U bfr[4];
            #pragma unroll
            for (int nc = 0; nc < 4; ++nc)
                bfr[nc].u = *(const uint4*)(Bp + nc * 4096 + ks * 512);
            #pragma unroll
            for (int t = 0; t < 4; ++t) {
                F4U a; a.u = *(const uint4*)(Apt[t] + ks * 32);
                #pragma unroll
                for (int nc = 0; nc < 4; ++nc)
                    acc[t][nc] = __builtin_amdgcn_mfma_f32_16x16x32_bf16(bfr[nc].s, a.s, acc[t][nc], 0, 0, 0);
            }
        }
        float sc = (n0 < 256) ? SCALE_L2E : 1.0f;
        u16* dst = (n0 < 256) ? q_s : k_s;
        #pragma unroll
        for (int t = 0; t < 4; ++t) {
            int l = (m0 & 1023) + w * 64 + t * 16 + l15;
            #pragma unroll
            for (int nc = 0; nc < 4; ++nc) {
                int nb = n0 + nc * 16 + quad * 4;  // 4 consecutive n = same head
                float4 b4 = *(const float4*)(bias + nb);
                int nl = nb & 255, h = nl >> 5, d0 = nl & 31;
                ushort4 o = { f2bf((acc[t][nc][0] + b4.x) * sc), f2bf((acc[t][nc][1] + b4.y) * sc),
                              f2bf((acc[t][nc][2] + b4.z) * sc), f2bf((acc[t][nc][3] + b4.w) * sc) };
                // fragment-order store: [bh][g32][s][lane'][8]
                int s_ = d0 >> 4, hib = (d0 >> 3) & 1, j0 = d0 & 7;
                int lanep = (l & 31) + (hib << 5);
                int g32 = l >> 5;
                *(ushort4*)(dst + ((((size_t)(b * 8 + h) * 32 + g32) * 2 + s_) * 64 + lanep) * 8 + j0) = o;
            }
        }
    } else {                               // ---- V: normal C, store fragment-order ----
        #pragma unroll
        for (int ks = 0; ks < 8; ++ks) {
            F4U bfr[4];
            #pragma unroll
            for (int nc = 0; nc < 4; ++nc)
                bfr[nc].u = *(const uint4*)(Bp + nc * 4096 + ks * 512);
            #pragma unroll
            for (int t = 0; t < 4; ++t) {
                F4U a; a.u = *(const uint4*)(Apt[t] + ks * 32);
                #pragma unroll
                for (int nc = 0; nc < 4; ++nc)
                    acc[t][nc] = __builtin_amdgcn_mfma_f32_16x16x32_bf16(a.s, bfr[nc].s, acc[t][nc], 0, 0, 0);
            }
        }
        #pragma unroll
        for (int t = 0; t < 4; ++t) {
            int lq = (m0 & 1023) + w * 64 + t * 16 + quad * 4;  // 4-aligned key base
            // stored position: bit-2/3 swap of within-group key index
            int lqp = (lq & ~12) | ((lq & 4) << 1) | ((lq & 8) >> 1);
            int g  = lq >> 4;          // 16-key group (0..63)
            int q0 = lqp & 15;         // in {0,4,8,12}
            #pragma unroll
            for (int nc = 0; nc < 4; ++nc) {
                int n = n0 + nc * 16 + l15;
                float bv = bias[n];
                int nl = n & 255, h = nl >> 5, d = nl & 31;
                ushort4 o = { f2bf(acc[t][nc][0] + bv), f2bf(acc[t][nc][1] + bv),
                              f2bf(acc[t][nc][2] + bv), f2bf(acc[t][nc][3] + bv) };
                // vt2[bh][g][lane = d + 32*(q0>>3)][8] ; 4 u16 at +(q0&7)
                *(ushort4*)(vt + (((size_t)(b * 8 + h) * 64 + g) * 64 + d + ((q0 >> 3) << 5)) * 8 + (q0 & 7)) = o;
            }
        }
    }
}

// ---- kernel 3: MFMA flash attention. v4: Q/K/V AND ctx all fragment-order.
// 512 blocks, 4 waves, 64 q-rows/wave, 64-key units, no LDS, K/V ping-pong.
// Every VMEM instruction is now a dense 1 KB (loads) or dense 512 B (O
// stores) region -- no multi-line gathers anywhere in the kernel.
__global__ __launch_bounds__(256, 2) void attn32_k(
    const u16* __restrict__ q_s,   // [bh][32][2][64][8] fragment-order (pre-scaled)
    const u16* __restrict__ k_s,   // [bh][32][2][64][8] fragment-order
    const u16* __restrict__ vt,    // [bh][64][64][8] fragment-order
    u16* __restrict__ ctx)         // [bh][32][2][64][8] fragment-order
{
    int tid = threadIdx.x;
    int w = tid >> 6, lane = tid & 63, col = lane & 31, hi = lane >> 5;
    int g = blockIdx.x;                      // 512 blocks = 4 qt x 128 bh
    int bh = (g & 7) | ((g >> 5) << 3);      // XCD-local bh grouping
    int q0 = ((g >> 3) & 3) * 256 + w * 64;  // 64 q-rows per wave

    const u16* qb = q_s + ((size_t)bh * 64) * 512 + lane * 8;
    const u16* kb = k_s + ((size_t)bh * 64) * 512 + lane * 8;
    const u16* vb = vt  + ((size_t)bh << 15) + lane * 8;

    F4U qf[2][2];   // B-frags: Q[q=col][d = s*16 + hi*8 + j] for 2 q-tiles
    #pragma unroll
    for (int t = 0; t < 2; ++t)
        #pragma unroll
        for (int s = 0; s < 2; ++s)
            qf[t][s].u = *(const uint4*)(qb + (size_t)(((q0 >> 5) + t) * 2 + s) * 512);

    f16f Z;                                  // persistent zero C-in for QK MFMA
    #pragma unroll
    for (int r = 0; r < 16; ++r) Z[r] = 0.f;

    f16f O[2];
    #pragma unroll
    for (int t = 0; t < 2; ++t)
        #pragma unroll
        for (int r = 0; r < 16; ++r) O[t][r] = 0.f;
    float psum[2] = {0.f, 0.f};

    F4U kA[2][2], kB[2][2], vA[2][2], vB[2][2];   // [key-half h][frag s]
    auto LD = [&](F4U (&kf)[2][2], F4U (&vf)[2][2], int key0) {
        int g16 = key0 >> 4;                       // base 16-key group (V)
        int g32 = key0 >> 5;                       // base 32-key group (K)
        #pragma unroll
        for (int h = 0; h < 2; ++h)
            #pragma unroll
            for (int s = 0; s < 2; ++s) {
                kf[h][s].u = *(const uint4*)(kb + (size_t)((g32 + h) * 2 + s) * 512);
                vf[h][s].u = *(const uint4*)(vb + (size_t)(g16 + h * 2 + s) * 512);
            }
    };
    auto STEP = [&](F4U (&kf)[2][2], F4U (&vf)[2][2]) {
        // phase 1: 8 independent QK MFMAs (4 chains of 2)
        f16f S[2][2];
        __builtin_amdgcn_s_setprio(1);
        #pragma unroll
        for (int t = 0; t < 2; ++t)
            #pragma unroll
            for (int h = 0; h < 2; ++h) {
                S[t][h] = __builtin_amdgcn_mfma_f32_32x32x16_bf16(kf[h][0].s, qf[t][0].s, Z, 0, 0, 0);
                S[t][h] = __builtin_amdgcn_mfma_f32_32x32x16_bf16(kf[h][1].s, qf[t][1].s, S[t][h], 0, 0, 0);
            }
        __builtin_amdgcn_s_setprio(0);
        // phase 2: 4 independent softmax+pack chains, natural order (no pswap)
        F4U pf[2][2][2];
        #pragma unroll
        for (int t = 0; t < 2; ++t)
            #pragma unroll
            for (int h = 0; h < 2; ++h) {
                float p[16];
                #pragma unroll
                for (int r = 0; r < 16; ++r) p[r] = __builtin_amdgcn_exp2f(S[t][h][r]);
                psum[t] += ((((p[0] + p[1]) + (p[2] + p[3])) + ((p[4] + p[5]) + (p[6] + p[7])))
                          + (((p[8] + p[9]) + (p[10] + p[11])) + ((p[12] + p[13]) + (p[14] + p[15]))));
                pf[t][h][0].u = make_uint4(cvt_pk_bf16(p[0],  p[1]),  cvt_pk_bf16(p[2],  p[3]),
                                           cvt_pk_bf16(p[4],  p[5]),  cvt_pk_bf16(p[6],  p[7]));
                pf[t][h][1].u = make_uint4(cvt_pk_bf16(p[8],  p[9]),  cvt_pk_bf16(p[10], p[11]),
                                           cvt_pk_bf16(p[12], p[13]), cvt_pk_bf16(p[14], p[15]));
            }
        // phase 3: 8 PV MFMAs (2 independent O-chains)
        __builtin_amdgcn_s_setprio(1);
        #pragma unroll
        for (int t = 0; t < 2; ++t) {
            O[t] = __builtin_amdgcn_mfma_f32_32x32x16_bf16(vf[0][0].s, pf[t][0][0].s, O[t], 0, 0, 0);
            O[t] = __builtin_amdgcn_mfma_f32_32x32x16_bf16(vf[0][1].s, pf[t][0][1].s, O[t], 0, 0, 0);
            O[t] = __builtin_amdgcn_mfma_f32_32x32x16_bf16(vf[1][0].s, pf[t][1][0].s, O[t], 0, 0, 0);
            O[t] = __builtin_amdgcn_mfma_f32_32x32x16_bf16(vf[1][1].s, pf[t][1][1].s, O[t], 0, 0, 0);
        }
        __builtin_amdgcn_s_setprio(0);
    };

    LD(kA, vA, 0);
    for (int u = 0; u < 16; u += 2) {            // 16 units of 64 keys
        LD(kB, vB, (u + 1) * 64);
        STEP(kA, vA);
        if (u + 2 < 16) LD(kA, vA, (u + 2) * 64);
        STEP(kB, vB);
    }

    u16* cb = ctx + ((size_t)bh * 64) * 512;
    #pragma unroll
    for (int t = 0; t < 2; ++t) {
        float ps = psum[t];
        ps += __shfl_xor(ps, 32);              // other hi-half holds other keys
        float inv = 1.0f / ps;
        // O C-layout: col = q, row = d = (r&3) + 8*(r>>2) + 4*hi
        // fragment-order store: per gi one dense 512 B region (64 lanes)
        int g32 = (q0 >> 5) + t;
        #pragma unroll
        for (int gi = 0; gi < 4; ++gi) {
            uint2 st;
            st.x = cvt_pk_bf16(O[t][4 * gi + 0] * inv, O[t][4 * gi + 1] * inv);
            st.y = cvt_pk_bf16(O[t][4 * gi + 2] * inv, O[t][4 * gi + 3] * inv);
            int s_ = gi >> 1, hib = gi & 1;
            *(uint2*)(cb + (size_t)(g32 * 2 + s_) * 512 + (col + (hib << 5)) * 8 + hi * 4) = st;
        }
    }
}

// ---- kernel 4: out = LN(ctx @ Wout^T + out_b + emb) -> fp32, fused.
// v4: ctx read from fragment order (4 dense 256B regions per instr);
// wout fragment-order (dense 1 KB B loads). 32 rows/block, 2 m-tiles/wave.
__global__ __launch_bounds__(256) void proj_ln_k(
    const int* __restrict__ seq,      // [M]
    const u16* __restrict__ ctx,      // [bh][32][2][64][8] fragment-order
    const u16* __restrict__ wout,     // [16][8][16][32] bf16 fragment-order
    const float* __restrict__ out_b,  // [256]
    const u16* __restrict__ tbl,      // [L,4,256] bf16
    float* __restrict__ out)          // [M,256] fp32
{
    __shared__ float2 sm[4][2][16];   // [wave][tile][l15(row)]
    int tid = threadIdx.x;
    int w = tid >> 6, lane = tid & 63, l15 = lane & 15, quad = lane >> 4;
    int m0 = blockIdx.x * 32;
    int b = m0 >> 10;

    // fragment-order B: dense 1 KB per (nb, ks) wave-load
    const u16* Bp = wout + (size_t)(w * 4) * 4096 + l15 * 32 + quad * 8;

    f4_t acc[2][4] = {{{0,0,0,0},{0,0,0,0},{0,0,0,0},{0,0,0,0}},
                      {{0,0,0,0},{0,0,0,0},{0,0,0,0},{0,0,0,0}}};

    int g32 = (m0 & 1023) >> 5;
    int s_ = quad >> 1, hib = quad & 1;      // d = quad*8..+7

    #pragma unroll
    for (int ks = 0; ks < 8; ++ks) {      // k = ks*32 + quad*8+j (head ks)
        F4U bf[4];
        #pragma unroll
        for (int nc = 0; nc < 4; ++nc)
            bf[nc].u = *(const uint4*)(Bp + nc * 4096 + ks * 512);
        #pragma unroll
        for (int t = 0; t < 2; ++t) {
            int lanep = (t * 16 + l15) + (hib << 5);
            F4U a; a.u = *(const uint4*)(ctx + (((size_t)(b * 8 + ks) * 32 + g32) * 2 + s_) * 512 + lanep * 8);
            #pragma unroll
            for (int nc = 0; nc < 4; ++nc)
                acc[t][nc] = __builtin_amdgcn_mfma_f32_16x16x32_bf16(bf[nc].s, a.s, acc[t][nc], 0, 0, 0);
        }
    }

    #pragma unroll
    for (int t = 0; t < 2; ++t) {
        int row = m0 + t * 16 + l15;
        int cls = seq[row];
        const u16* ep = tbl + ((size_t)((row & 1023) * 4 + cls)) * 256;
        float s = 0.f, q = 0.f;
        #pragma unroll
        for (int nc = 0; nc < 4; ++nc) {
            int nb = w * 64 + nc * 16 + quad * 4;
            float4 bb = *(const float4*)(out_b + nb);
            ushort4 e4 = *(const ushort4*)(ep + nb);
            acc[t][nc][0] += bb.x + bf2f(e4.x);
            acc[t][nc][1] += bb.y + bf2f(e4.y);
            acc[t][nc][2] += bb.z + bf2f(e4.z);
            acc[t][nc][3] += bb.w + bf2f(e4.w);
            #pragma unroll
            for (int r = 0; r < 4; ++r) { s += acc[t][nc][r]; q += acc[t][nc][r] * acc[t][nc][r]; }
        }
        s += __shfl_xor(s, 16);  q += __shfl_xor(q, 16);
        s += __shfl_xor(s, 32);  q += __shfl_xor(q, 32);
        if (quad == 0) sm[w][t][l15] = make_float2(s, q);
    }
    __syncthreads();
    #pragma unroll
    for (int t = 0; t < 2; ++t) {
        int row = m0 + t * 16 + l15;
        float2 t0 = sm[0][t][l15], t1 = sm[1][t][l15], t2 = sm[2][t][l15], t3 = sm[3][t][l15];
        float s = (t0.x + t1.x) + (t2.x + t3.x);
        float q = (t0.y + t1.y) + (t2.y + t3.y);
        float mean = s * (1.0f / 256.0f);
        float var  = q * (1.0f / 256.0f) - mean * mean;
        float rstd = rsqrtf(var + 1e-5f);
        #pragma unroll
        for (int nc = 0; nc < 4; ++nc) {
            float4 o = { (acc[t][nc][0] - mean) * rstd, (acc[t][nc][1] - mean) * rstd,
                         (acc[t][nc][2] - mean) * rstd, (acc[t][nc][3] - mean) * rstd };
            *(float4*)(out + (size_t)row * 256 + w * 64 + nc * 16 + quad * 4) = o;
        }
    }
}

extern "C" void kernel_launch(void* const* d_in, const int* in_sizes, int n_in,
                              void* d_out, int out_size, void* d_ws, size_t ws_size,
                              hipStream_t stream) {
    const int*   seq       = (const int*)d_in[0];
    const float* emb_w     = (const float*)d_in[1];
    const float* emb_b     = (const float*)d_in[2];
    const float* in_proj_w = (const float*)d_in[3];
    const float* in_proj_b = (const float*)d_in[4];
    const float* out_w     = (const float*)d_in[5];
    const float* out_b     = (const float*)d_in[6];
    float*       out       = (float*)d_out;

    const size_t P   = (size_t)M_ * 256;     // 4,194,304 els
    const size_t TBL = (size_t)L_ * 4 * 256; // 1,048,576 els (2 MB)
    u16* ws   = (u16*)d_ws;
    u16* tbl  = ws;                  //  2 MB [L,4,256]
    u16* q_s  = ws + TBL;            //  8 MB [bh][32][2][64][8] fragment-order
    u16* k_s  = q_s + P;             //  8 MB [bh][32][2][64][8] fragment-order
    u16* vt   = k_s + P;             //  8 MB [bh][64][64][8] fragment-order
    u16* ctx  = vt + P;              //  8 MB [bh][32][2][64][8] fragment-order
    u16* wqkv = ctx + P;             //  384 KB fragment-order
    u16* wout = wqkv + 768 * 256;    //  128 KB fragment-order

    table_conv_k<<<1024, 256, 0, stream>>>(emb_w, emb_b, in_proj_w, out_w, tbl, wqkv);
    gemm_qkv_mfma_k<<<dim3(12, 64), 256, 0, stream>>>(seq, tbl, wqkv, in_proj_b, q_s, k_s, vt);
    attn32_k<<<512, 256, 0, stream>>>(q_s, k_s, vt, ctx);
    proj_ln_k<<<M_ / 32, 256, 0, stream>>>(seq, ctx, wout, out_b, tbl, out);
}